// Round 9
// baseline (48.176 us; speedup 1.0000x reference)
//
#include <hip/hip_runtime.h>

#define L_LAYERS 783
#define L_PAD    784           // = SEGF*GF = SEGS*GS
#define B_BATCH  8192
#define N_SITES  784
#define K_KRAUS  16

// FAST path geometry
#define SEGF     14
#define GF       56
// FALLBACK geometry (round-4 path, proven within 15 MB workspace)
#define SEGS     28
#define GS       28
#define TPBS     128

// ---------------------------------------------------------------------------
// Hermitian-reduced formulation.
// State v = (s00, s11, u, w), sigma = [[s00, u+iw], [u-iw, s11]].
// Per layer: v' = R v, R = C + D*xx0 + B*xx1 (D = A - C, since xx0+xx3 = 1),
// xx = outer(x,x)/|x|^2. Tc per layer: 48 floats = [C(16) | D(16) | B(16)].
// Pad layers (l >= 783): R = I  (C=I, D=0, B=0).
// ---------------------------------------------------------------------------
__global__ void __launch_bounds__(256)
build_T(const float* __restrict__ kr, const float* __restrict__ ki,
        float* __restrict__ Tc) {
    __shared__ float lr[K_KRAUS * 16];
    __shared__ float li[K_KRAUS * 16];
    __shared__ float gr[48], gi[48];
    int l = blockIdx.x;
    int t = threadIdx.x;
    float* o = Tc + (size_t)l * 48;

    if (l >= L_LAYERS) {                        // identity pad layer
        if (t < 16) {
            int row = t >> 2, col = t & 3;
            o[t]      = (row == col) ? 1.f : 0.f;
            o[16 + t] = 0.f;
            o[32 + t] = 0.f;
        }
        return;
    }

    lr[t] = kr[(size_t)l * 256 + t];
    li[t] = ki[(size_t)l * 256 + t];
    __syncthreads();

    if (t < 192) {
        int e = t >> 2, chunk = t & 3;
        int ci = e >> 4;                        // 0,1,2
        int c = ci >> 1, d = (ci + 1) >> 1;     // (0,0),(0,1),(1,1)
        int m = (e >> 2) & 3, q = e & 3;
        int i1 = m >> 1, j1 = m & 1, i2 = q >> 1, j2 = q & 1;
        int off1 = c * 4 + 2 * i1 + i2;
        int off2 = d * 4 + 2 * j1 + j2;
        float ar = 0.f, ai = 0.f;
        #pragma unroll
        for (int kk = 0; kk < 4; ++kk) {
            int kbase = (chunk * 4 + kk) * 16;
            #pragma unroll
            for (int a = 0; a < 2; ++a) {
                int x1 = kbase + a * 8 + off1;
                int x2 = kbase + a * 8 + off2;
                float k1r = lr[x1], k1i = li[x1];
                float k2r = lr[x2], k2i = li[x2];
                ar += k1r * k2r + k1i * k2i;    // K1 * conj(K2)
                ai += k1i * k2r - k1r * k2i;
            }
        }
        ar += __shfl_xor(ar, 1); ar += __shfl_xor(ar, 2);
        ai += __shfl_xor(ai, 1); ai += __shfl_xor(ai, 2);
        if (chunk == 0) { gr[e] = ar; gi[e] = ai; }
    }
    __syncthreads();

    if (t < 16) {
        int row = t >> 2, col = t & 3;
        int ci = (row == 0) ? 0 : (row == 1) ? 2 : 1;
        int base = ci * 16;
        float Ur[4], Ui[4];
        #pragma unroll
        for (int q = 0; q < 4; ++q) {
            if (col == 0)      { Ur[q] = gr[base + q];      Ui[q] = gi[base + q]; }
            else if (col == 1) { Ur[q] = gr[base + 12 + q]; Ui[q] = gi[base + 12 + q]; }
            else {
                float t1r = gr[base + 4 + q], t1i = gi[base + 4 + q];
                float t2r = gr[base + 8 + q], t2i = gi[base + 8 + q];
                if (col == 2) { Ur[q] = t1r + t2r;    Ui[q] = t1i + t2i; }
                else          { Ur[q] = -(t1i - t2i); Ui[q] = t1r - t2r; }   // i*(T1-T2)
            }
        }
        float A, Bc, Cc;
        if (row == 3) { A = Ui[0]; Bc = Ui[1] + Ui[2]; Cc = Ui[3]; }
        else          { A = Ur[0]; Bc = Ur[1] + Ur[2]; Cc = Ur[3]; }
        o[t]      = Cc;
        o[16 + t] = A - Cc;
        o[32 + t] = Bc;
    }
}

// ---------------------------------------------------------------------------
// FAST kernel 2: per (batch-chunk, segment) product of SEGF transfer matrices.
// 128 threads, each owning TWO batch chains (t, t+128) -> 2 independent FMA
// streams per thread; Tc scalars (s_load path) shared across both chains.
// X staged through LDS in two 7-site phases (14 KB). P SoA.
// ---------------------------------------------------------------------------
__global__ void __launch_bounds__(128, 4)
seg_fused(const float* __restrict__ X, const float* __restrict__ Tc,
          float* __restrict__ P) {
    __shared__ float2 xxs[256 * 7];             // 14336 B
    int t  = threadIdx.x;                       // 0..127
    int s  = blockIdx.y;
    int ls = s * SEGF;
    int b0 = blockIdx.x * 256;
    const float* tl0 = Tc + (size_t)ls * 48;    // wave-uniform base -> s_load
    const float2* Xp = (const float2*)X;

    float pAa[16], pBa[16], pAb[16], pBb[16];
    #pragma unroll
    for (int i = 0; i < 16; ++i) {
        float id = (i % 5 == 0) ? 1.f : 0.f;
        pAa[i] = id; pAb[i] = id;
    }

// stage 7 sites (half H) for 256 batches with 128 threads (14 iters)
#define STAGE(H)                                                                \
    {                                                                           \
        _Pragma("unroll")                                                       \
        for (int e = 0; e < 14; ++e) {                                          \
            int idx  = t + e * 128;             /* 0..1791 */                   \
            int row  = idx / 7;                                                 \
            int col  = idx - row * 7;                                           \
            int site = ls + 1 + (H) * 7 + col;                                  \
            site = site < (N_SITES - 1) ? site : (N_SITES - 1);                 \
            float2 xv = Xp[(size_t)(b0 + row) * N_SITES + site];                \
            float inv = __builtin_amdgcn_rcpf(fmaf(xv.x, xv.x, xv.y * xv.y));   \
            xxs[row * 7 + col] = make_float2(xv.x * xv.x * inv,                 \
                                             xv.x * xv.y * inv);                \
        }                                                                       \
    }

// one layer, both chains; Tc coefficients shared (single SGPR->VGPR movs)
#define STEP2(SA, DA, SB, DB, I, COL)                                           \
    {                                                                           \
        const float* tl = tl0 + (I) * 48;       /* uniform -> s_load */         \
        float2 xa = xxs[t * 7 + (COL)];                                         \
        float2 xb = xxs[(t + 128) * 7 + (COL)];                                 \
        float Ra[16], Rb[16];                                                   \
        _Pragma("unroll")                                                       \
        for (int e = 0; e < 16; ++e) {                                          \
            float cv = tl[e];                                                   \
            float dv = tl[16 + e];                                              \
            float bv = tl[32 + e];                                              \
            Ra[e] = fmaf(bv, xa.y, fmaf(dv, xa.x, cv));                         \
            Rb[e] = fmaf(bv, xb.y, fmaf(dv, xb.x, cv));                         \
        }                                                                       \
        _Pragma("unroll")                                                       \
        for (int r = 0; r < 4; ++r) {                                           \
            _Pragma("unroll")                                                   \
            for (int cc = 0; cc < 4; ++cc) {                                    \
                DA[r * 4 + cc] =                                                \
                    fmaf(Ra[r * 4 + 0], SA[cc],                                 \
                    fmaf(Ra[r * 4 + 1], SA[4 + cc],                             \
                    fmaf(Ra[r * 4 + 2], SA[8 + cc],                             \
                         Ra[r * 4 + 3] * SA[12 + cc])));                        \
                DB[r * 4 + cc] =                                                \
                    fmaf(Rb[r * 4 + 0], SB[cc],                                 \
                    fmaf(Rb[r * 4 + 1], SB[4 + cc],                             \
                    fmaf(Rb[r * 4 + 2], SB[8 + cc],                             \
                         Rb[r * 4 + 3] * SB[12 + cc])));                        \
            }                                                                   \
        }                                                                       \
    }

    // ---- half 0: layers ls+0 .. ls+6 ----
    STAGE(0);
    __syncthreads();
    STEP2(pAa, pBa, pAb, pBb, 0, 0); STEP2(pBa, pAa, pBb, pAb, 1, 1);
    STEP2(pAa, pBa, pAb, pBb, 2, 2); STEP2(pBa, pAa, pBb, pAb, 3, 3);
    STEP2(pAa, pBa, pAb, pBb, 4, 4); STEP2(pBa, pAa, pBb, pAb, 5, 5);
    STEP2(pAa, pBa, pAb, pBb, 6, 6);            // result in pB*
    __syncthreads();                            // before restage

    // ---- half 1: layers ls+7 .. ls+13 ----
    STAGE(1);
    __syncthreads();
    STEP2(pBa, pAa, pBb, pAb, 7, 0);  STEP2(pAa, pBa, pAb, pBb, 8, 1);
    STEP2(pBa, pAa, pBb, pAb, 9, 2);  STEP2(pAa, pBa, pAb, pBb, 10, 3);
    STEP2(pBa, pAa, pBb, pAb, 11, 4); STEP2(pAa, pBa, pAb, pBb, 12, 5);
    STEP2(pBa, pAa, pBb, pAb, 13, 6);           // result in pA*
#undef STEP2
#undef STAGE

    int ba = b0 + t;
    int bb = b0 + t + 128;
    #pragma unroll
    for (int i = 0; i < 16; ++i) {
        P[((size_t)(s * 16 + i)) * B_BATCH + ba] = pAa[i];
        P[((size_t)(s * 16 + i)) * B_BATCH + bb] = pAb[i];
    }
}

// ---------------------------------------------------------------------------
// FAST kernel 3: two-level combine for G=56 (8 groups x 7-chain, then 8-chain).
// ---------------------------------------------------------------------------
__global__ void __launch_bounds__(256)
combine56(const float* __restrict__ X, const float* __restrict__ P,
          float* __restrict__ out) {
    __shared__ float q[256][17];
    int t = threadIdx.x;
    int j = t >> 5, bl = t & 31;
    int b = blockIdx.x * 32 + bl;

    float qa[16], qb[16];
    #pragma unroll
    for (int i = 0; i < 16; ++i) qa[i] = (i % 5 == 0) ? 1.f : 0.f;

#define CSTEP(SRC, DST, K)                                                      \
    {                                                                           \
        float m[16];                                                            \
        _Pragma("unroll")                                                       \
        for (int i = 0; i < 16; ++i)                                            \
            m[i] = P[((size_t)((j * 7 + (K)) * 16 + i)) * B_BATCH + b];         \
        _Pragma("unroll")                                                       \
        for (int r = 0; r < 4; ++r) {                                           \
            _Pragma("unroll")                                                   \
            for (int cc = 0; cc < 4; ++cc)                                      \
                DST[r * 4 + cc] =                                               \
                    fmaf(m[r * 4 + 0], SRC[cc],                                 \
                    fmaf(m[r * 4 + 1], SRC[4 + cc],                             \
                    fmaf(m[r * 4 + 2], SRC[8 + cc],                             \
                         m[r * 4 + 3] * SRC[12 + cc])));                        \
        }                                                                       \
    }
    CSTEP(qa, qb, 0); CSTEP(qb, qa, 1);
    CSTEP(qa, qb, 2); CSTEP(qb, qa, 3);
    CSTEP(qa, qb, 4); CSTEP(qb, qa, 5);
    CSTEP(qa, qb, 6);                          // result in qb
#undef CSTEP

    #pragma unroll
    for (int i = 0; i < 16; ++i) q[t][i] = qb[i];
    __syncthreads();

    if (t < 32) {
        int b2 = blockIdx.x * 32 + t;
        const float2* Xp = (const float2*)X;
        float2 xv = Xp[(size_t)b2 * N_SITES];
        float inv = __builtin_amdgcn_rcpf(fmaf(xv.x, xv.x, xv.y * xv.y));
        float v0 = xv.x * xv.x * inv;
        float v1 = xv.y * xv.y * inv;
        float v2 = xv.x * xv.y * inv;
        float v3 = 0.f;
        #pragma unroll
        for (int jj = 0; jj < 8; ++jj) {
            const float* qq = q[jj * 32 + t];
            float n0 = fmaf(qq[0],  v0, fmaf(qq[1],  v1, fmaf(qq[2],  v2, qq[3]  * v3)));
            float n1 = fmaf(qq[4],  v0, fmaf(qq[5],  v1, fmaf(qq[6],  v2, qq[7]  * v3)));
            float n2 = fmaf(qq[8],  v0, fmaf(qq[9],  v1, fmaf(qq[10], v2, qq[11] * v3)));
            float n3 = fmaf(qq[12], v0, fmaf(qq[13], v1, fmaf(qq[14], v2, qq[15] * v3)));
            v0 = n0; v1 = n1; v2 = n2; v3 = n3;
        }
        out[b2] = v0;
    }
}

// ---------------------------------------------------------------------------
// FALLBACK kernels (round-4 path, proven within 15 MB workspace)
// ---------------------------------------------------------------------------
__global__ void __launch_bounds__(TPBS)
seg_slow(const float* __restrict__ X, const float* __restrict__ Tc,
         float* __restrict__ P) {
    __shared__ float4 tcs4[SEGS * 12];
    __shared__ float2 xxs[TPBS][SEGS + 1];
    int t  = threadIdx.x;
    int s  = blockIdx.y;
    int ls = s * SEGS;
    int b0 = blockIdx.x * TPBS;

    const float4* tg = (const float4*)Tc + (size_t)ls * 12;
    #pragma unroll
    for (int i = t; i < SEGS * 12; i += TPBS) tcs4[i] = tg[i];

    const float2* Xp = (const float2*)X;
    for (int idx = t; idx < SEGS * TPBS; idx += TPBS) {
        int col  = idx % SEGS;
        int row  = idx / SEGS;
        int site = ls + 1 + col;
        site = site < (N_SITES - 1) ? site : (N_SITES - 1);
        float2 xv = Xp[(size_t)(b0 + row) * N_SITES + site];
        float inv = __builtin_amdgcn_rcpf(fmaf(xv.x, xv.x, xv.y * xv.y));
        xxs[row][col] = make_float2(xv.x * xv.x * inv, xv.x * xv.y * inv);
    }
    __syncthreads();

    float pA[16], pB[16];
    #pragma unroll
    for (int i = 0; i < 16; ++i) pA[i] = (i % 5 == 0) ? 1.f : 0.f;

#define STEP(SRC, DST, I)                                                       \
    {                                                                           \
        float2 xx = xxs[t][I];                                                  \
        float R[16];                                                            \
        _Pragma("unroll")                                                       \
        for (int r = 0; r < 4; ++r) {                                           \
            float4 cv = tcs4[(I) * 12 + r];                                     \
            float4 dv = tcs4[(I) * 12 + 4 + r];                                 \
            float4 bv = tcs4[(I) * 12 + 8 + r];                                 \
            R[r * 4 + 0] = fmaf(bv.x, xx.y, fmaf(dv.x, xx.x, cv.x));            \
            R[r * 4 + 1] = fmaf(bv.y, xx.y, fmaf(dv.y, xx.x, cv.y));            \
            R[r * 4 + 2] = fmaf(bv.z, xx.y, fmaf(dv.z, xx.x, cv.z));            \
            R[r * 4 + 3] = fmaf(bv.w, xx.y, fmaf(dv.w, xx.x, cv.w));            \
        }                                                                       \
        _Pragma("unroll")                                                       \
        for (int r = 0; r < 4; ++r) {                                           \
            _Pragma("unroll")                                                   \
            for (int cc = 0; cc < 4; ++cc)                                      \
                DST[r * 4 + cc] =                                               \
                    fmaf(R[r * 4 + 0], SRC[cc],                                 \
                    fmaf(R[r * 4 + 1], SRC[4 + cc],                             \
                    fmaf(R[r * 4 + 2], SRC[8 + cc],                             \
                         R[r * 4 + 3] * SRC[12 + cc])));                        \
        }                                                                       \
    }

    #pragma unroll
    for (int i = 0; i < SEGS; i += 2) {
        STEP(pA, pB, i);
        STEP(pB, pA, i + 1);
    }
#undef STEP

    int b = b0 + t;
    #pragma unroll
    for (int i = 0; i < 16; ++i)
        P[((size_t)(s * 16 + i)) * B_BATCH + b] = pA[i];
}

__global__ void __launch_bounds__(256)
combine28(const float* __restrict__ X, const float* __restrict__ P,
          float* __restrict__ out) {
    __shared__ float q[256][17];
    int t  = threadIdx.x;
    int j  = t >> 6;
    int bl = t & 63;
    int b  = blockIdx.x * 64 + bl;

    float qa[16], qb[16];
    #pragma unroll
    for (int i = 0; i < 16; ++i) qa[i] = (i % 5 == 0) ? 1.f : 0.f;

#define CSTEP(SRC, DST, K)                                                      \
    {                                                                           \
        float m[16];                                                            \
        _Pragma("unroll")                                                       \
        for (int i = 0; i < 16; ++i)                                            \
            m[i] = P[((size_t)((j * 7 + (K)) * 16 + i)) * B_BATCH + b];         \
        _Pragma("unroll")                                                       \
        for (int r = 0; r < 4; ++r) {                                           \
            _Pragma("unroll")                                                   \
            for (int cc = 0; cc < 4; ++cc)                                      \
                DST[r * 4 + cc] =                                               \
                    fmaf(m[r * 4 + 0], SRC[cc],                                 \
                    fmaf(m[r * 4 + 1], SRC[4 + cc],                             \
                    fmaf(m[r * 4 + 2], SRC[8 + cc],                             \
                         m[r * 4 + 3] * SRC[12 + cc])));                        \
        }                                                                       \
    }
    CSTEP(qa, qb, 0); CSTEP(qb, qa, 1);
    CSTEP(qa, qb, 2); CSTEP(qb, qa, 3);
    CSTEP(qa, qb, 4); CSTEP(qb, qa, 5);
    CSTEP(qa, qb, 6);
#undef CSTEP

    #pragma unroll
    for (int i = 0; i < 16; ++i) q[t][i] = qb[i];
    __syncthreads();

    if (t < 64) {
        int b2 = blockIdx.x * 64 + t;
        const float2* Xp = (const float2*)X;
        float2 xv = Xp[(size_t)b2 * N_SITES];
        float inv = __builtin_amdgcn_rcpf(fmaf(xv.x, xv.x, xv.y * xv.y));
        float v0 = xv.x * xv.x * inv;
        float v1 = xv.y * xv.y * inv;
        float v2 = xv.x * xv.y * inv;
        float v3 = 0.f;
        #pragma unroll
        for (int jj = 0; jj < 4; ++jj) {
            const float* qq = q[jj * 64 + t];
            float n0 = fmaf(qq[0],  v0, fmaf(qq[1],  v1, fmaf(qq[2],  v2, qq[3]  * v3)));
            float n1 = fmaf(qq[4],  v0, fmaf(qq[5],  v1, fmaf(qq[6],  v2, qq[7]  * v3)));
            float n2 = fmaf(qq[8],  v0, fmaf(qq[9],  v1, fmaf(qq[10], v2, qq[11] * v3)));
            float n3 = fmaf(qq[12], v0, fmaf(qq[13], v1, fmaf(qq[14], v2, qq[15] * v3)));
            v0 = n0; v1 = n1; v2 = n2; v3 = n3;
        }
        out[b2] = v0;
    }
}

// ---------------------------------------------------------------------------
extern "C" void kernel_launch(void* const* d_in, const int* in_sizes, int n_in,
                              void* d_out, int out_size, void* d_ws, size_t ws_size,
                              hipStream_t stream) {
    const float* X  = (const float*)d_in[0];
    const float* kr = (const float*)d_in[1];
    const float* ki = (const float*)d_in[2];
    float* out = (float*)d_out;

    float* Tc = (float*)d_ws;
    const size_t Tb  = (size_t)L_PAD * 48 * sizeof(float);         // 150,528 (256-mult)
    const size_t Pfb = (size_t)GF * 16 * B_BATCH * sizeof(float);  // 29,360,128

    build_T<<<L_PAD, 256, 0, stream>>>(kr, ki, Tc);

    if (ws_size >= Tb + Pfb) {
        // FAST path: fused stage+product, scalar-path Tc, 2-batch ILP
        float* P = (float*)((char*)d_ws + Tb);
        dim3 gs(B_BATCH / 256, GF);
        seg_fused<<<gs, 128, 0, stream>>>(X, Tc, P);
        combine56<<<B_BATCH / 32, 256, 0, stream>>>(X, P, out);
    } else {
        // FALLBACK (round-4 path, 14.8 MB)
        float* P = (float*)((char*)d_ws + Tb);
        dim3 gs(B_BATCH / TPBS, GS);
        seg_slow<<<gs, TPBS, 0, stream>>>(X, Tc, P);
        combine28<<<B_BATCH / 64, 256, 0, stream>>>(X, P, out);
    }
}

// Round 10
// 43.517 us; speedup vs baseline: 1.1070x; 1.1070x over previous
//
#include <hip/hip_runtime.h>

#define L_LAYERS 783
#define L_PAD    784           // = SEGF*GF = SEGS*GS
#define B_BATCH  8192
#define N_SITES  784
#define K_KRAUS  16

// FAST path geometry
#define SEGF     14
#define GF       56
// FALLBACK geometry (round-4 path, proven within 15 MB workspace)
#define SEGS     28
#define GS       28
#define TPBS     128

// ---------------------------------------------------------------------------
// Hermitian-reduced formulation.
// State v = (s00, s11, u, w), sigma = [[s00, u+iw], [u-iw, s11]].
// Per layer: v' = R v, R = C + D*xx0 + B*xx1 (D = A - C, since xx0+xx3 = 1),
// xx = outer(x,x)/|x|^2. Tc per layer: 48 floats = [C(16) | D(16) | B(16)].
// Pad layers (l >= 783): R = I  (C=I, D=0, B=0).
// ---------------------------------------------------------------------------
__global__ void __launch_bounds__(256)
build_T(const float* __restrict__ kr, const float* __restrict__ ki,
        float* __restrict__ Tc) {
    __shared__ float lr[K_KRAUS * 16];
    __shared__ float li[K_KRAUS * 16];
    __shared__ float gr[48], gi[48];
    int l = blockIdx.x;
    int t = threadIdx.x;
    float* o = Tc + (size_t)l * 48;

    if (l >= L_LAYERS) {                        // identity pad layer
        if (t < 16) {
            int row = t >> 2, col = t & 3;
            o[t]      = (row == col) ? 1.f : 0.f;
            o[16 + t] = 0.f;
            o[32 + t] = 0.f;
        }
        return;
    }

    lr[t] = kr[(size_t)l * 256 + t];
    li[t] = ki[(size_t)l * 256 + t];
    __syncthreads();

    if (t < 192) {
        int e = t >> 2, chunk = t & 3;
        int ci = e >> 4;                        // 0,1,2
        int c = ci >> 1, d = (ci + 1) >> 1;     // (0,0),(0,1),(1,1)
        int m = (e >> 2) & 3, q = e & 3;
        int i1 = m >> 1, j1 = m & 1, i2 = q >> 1, j2 = q & 1;
        int off1 = c * 4 + 2 * i1 + i2;
        int off2 = d * 4 + 2 * j1 + j2;
        float ar = 0.f, ai = 0.f;
        #pragma unroll
        for (int kk = 0; kk < 4; ++kk) {
            int kbase = (chunk * 4 + kk) * 16;
            #pragma unroll
            for (int a = 0; a < 2; ++a) {
                int x1 = kbase + a * 8 + off1;
                int x2 = kbase + a * 8 + off2;
                float k1r = lr[x1], k1i = li[x1];
                float k2r = lr[x2], k2i = li[x2];
                ar += k1r * k2r + k1i * k2i;    // K1 * conj(K2)
                ai += k1i * k2r - k1r * k2i;
            }
        }
        ar += __shfl_xor(ar, 1); ar += __shfl_xor(ar, 2);
        ai += __shfl_xor(ai, 1); ai += __shfl_xor(ai, 2);
        if (chunk == 0) { gr[e] = ar; gi[e] = ai; }
    }
    __syncthreads();

    if (t < 16) {
        int row = t >> 2, col = t & 3;
        int ci = (row == 0) ? 0 : (row == 1) ? 2 : 1;
        int base = ci * 16;
        float Ur[4], Ui[4];
        #pragma unroll
        for (int q = 0; q < 4; ++q) {
            if (col == 0)      { Ur[q] = gr[base + q];      Ui[q] = gi[base + q]; }
            else if (col == 1) { Ur[q] = gr[base + 12 + q]; Ui[q] = gi[base + 12 + q]; }
            else {
                float t1r = gr[base + 4 + q], t1i = gi[base + 4 + q];
                float t2r = gr[base + 8 + q], t2i = gi[base + 8 + q];
                if (col == 2) { Ur[q] = t1r + t2r;    Ui[q] = t1i + t2i; }
                else          { Ur[q] = -(t1i - t2i); Ui[q] = t1r - t2r; }   // i*(T1-T2)
            }
        }
        float A, Bc, Cc;
        if (row == 3) { A = Ui[0]; Bc = Ui[1] + Ui[2]; Cc = Ui[3]; }
        else          { A = Ur[0]; Bc = Ur[1] + Ur[2]; Cc = Ur[3]; }
        o[t]      = Cc;
        o[16 + t] = A - Cc;
        o[32 + t] = Bc;
    }
}

// ---------------------------------------------------------------------------
// FAST kernel 2: per (batch, segment) product of SEGF transfer matrices.
// NO xx staging / NO transpose: each thread loads its OWN row's 14 sites
// (contiguous 112 B span, 1-2 cache lines; X is L3-resident) as 14
// independent dwordx2 loads hoisted ahead of compute. Single barrier total
// (Tc -> LDS). P stored SoA: P[(s*16 + i) * B + b].
// ---------------------------------------------------------------------------
__global__ void __launch_bounds__(256, 4)
seg_fused(const float* __restrict__ X, const float* __restrict__ Tc,
          float* __restrict__ P) {
    __shared__ float4 tcs4[SEGF * 12];          // 2688 B
    int t  = threadIdx.x;
    int s  = blockIdx.y;
    int ls = s * SEGF;
    int b  = blockIdx.x * 256 + t;

    const float4* tg = (const float4*)Tc + (size_t)ls * 12;
    if (t < SEGF * 12) tcs4[t] = tg[t];         // 168 elems
    __syncthreads();

    // hoisted per-thread loads: sites ls+1 .. ls+14 of own batch row
    const float2* xp = (const float2*)X + (size_t)b * N_SITES;
    float2 xv[SEGF];
    #pragma unroll
    for (int i = 0; i < SEGF; ++i) {
        int site = ls + 1 + i;
        site = site < (N_SITES - 1) ? site : (N_SITES - 1);   // pad clamp
        xv[i] = xp[site];
    }

    float pA[16], pB[16];
    #pragma unroll
    for (int i = 0; i < 16; ++i) pA[i] = (i % 5 == 0) ? 1.f : 0.f;

#define STEP(SRC, DST, I)                                                       \
    {                                                                           \
        float2 x  = xv[I];                                                      \
        float inv = __builtin_amdgcn_rcpf(fmaf(x.x, x.x, x.y * x.y));           \
        float xx0 = x.x * x.x * inv;                                            \
        float xx1 = x.x * x.y * inv;                                            \
        float R[16];                                                            \
        _Pragma("unroll")                                                       \
        for (int r = 0; r < 4; ++r) {                                           \
            float4 cv = tcs4[(I) * 12 + r];                                     \
            float4 dv = tcs4[(I) * 12 + 4 + r];                                 \
            float4 bv = tcs4[(I) * 12 + 8 + r];                                 \
            R[r * 4 + 0] = fmaf(bv.x, xx1, fmaf(dv.x, xx0, cv.x));              \
            R[r * 4 + 1] = fmaf(bv.y, xx1, fmaf(dv.y, xx0, cv.y));              \
            R[r * 4 + 2] = fmaf(bv.z, xx1, fmaf(dv.z, xx0, cv.z));              \
            R[r * 4 + 3] = fmaf(bv.w, xx1, fmaf(dv.w, xx0, cv.w));              \
        }                                                                       \
        _Pragma("unroll")                                                       \
        for (int r = 0; r < 4; ++r) {                                           \
            _Pragma("unroll")                                                   \
            for (int cc = 0; cc < 4; ++cc)                                      \
                DST[r * 4 + cc] =                                               \
                    fmaf(R[r * 4 + 0], SRC[cc],                                 \
                    fmaf(R[r * 4 + 1], SRC[4 + cc],                             \
                    fmaf(R[r * 4 + 2], SRC[8 + cc],                             \
                         R[r * 4 + 3] * SRC[12 + cc])));                        \
        }                                                                       \
    }

    #pragma unroll
    for (int i = 0; i < SEGF; i += 2) {         // SEGF even -> ends in pA
        STEP(pA, pB, i);
        STEP(pB, pA, i + 1);
    }
#undef STEP

    #pragma unroll
    for (int i = 0; i < 16; ++i)
        P[((size_t)(s * 16 + i)) * B_BATCH + b] = pA[i];
}

// ---------------------------------------------------------------------------
// FAST kernel 3: two-level combine for G=56 (8 groups x 7-chain, then 8-chain).
// ---------------------------------------------------------------------------
__global__ void __launch_bounds__(256)
combine56(const float* __restrict__ X, const float* __restrict__ P,
          float* __restrict__ out) {
    __shared__ float q[256][17];
    int t = threadIdx.x;
    int j = t >> 5, bl = t & 31;
    int b = blockIdx.x * 32 + bl;

    float qa[16], qb[16];
    #pragma unroll
    for (int i = 0; i < 16; ++i) qa[i] = (i % 5 == 0) ? 1.f : 0.f;

#define CSTEP(SRC, DST, K)                                                      \
    {                                                                           \
        float m[16];                                                            \
        _Pragma("unroll")                                                       \
        for (int i = 0; i < 16; ++i)                                            \
            m[i] = P[((size_t)((j * 7 + (K)) * 16 + i)) * B_BATCH + b];         \
        _Pragma("unroll")                                                       \
        for (int r = 0; r < 4; ++r) {                                           \
            _Pragma("unroll")                                                   \
            for (int cc = 0; cc < 4; ++cc)                                      \
                DST[r * 4 + cc] =                                               \
                    fmaf(m[r * 4 + 0], SRC[cc],                                 \
                    fmaf(m[r * 4 + 1], SRC[4 + cc],                             \
                    fmaf(m[r * 4 + 2], SRC[8 + cc],                             \
                         m[r * 4 + 3] * SRC[12 + cc])));                        \
        }                                                                       \
    }
    CSTEP(qa, qb, 0); CSTEP(qb, qa, 1);
    CSTEP(qa, qb, 2); CSTEP(qb, qa, 3);
    CSTEP(qa, qb, 4); CSTEP(qb, qa, 5);
    CSTEP(qa, qb, 6);                          // result in qb
#undef CSTEP

    #pragma unroll
    for (int i = 0; i < 16; ++i) q[t][i] = qb[i];
    __syncthreads();

    if (t < 32) {
        int b2 = blockIdx.x * 32 + t;
        const float2* Xp = (const float2*)X;
        float2 xv = Xp[(size_t)b2 * N_SITES];
        float inv = __builtin_amdgcn_rcpf(fmaf(xv.x, xv.x, xv.y * xv.y));
        float v0 = xv.x * xv.x * inv;
        float v1 = xv.y * xv.y * inv;
        float v2 = xv.x * xv.y * inv;
        float v3 = 0.f;
        #pragma unroll
        for (int jj = 0; jj < 8; ++jj) {
            const float* qq = q[jj * 32 + t];
            float n0 = fmaf(qq[0],  v0, fmaf(qq[1],  v1, fmaf(qq[2],  v2, qq[3]  * v3)));
            float n1 = fmaf(qq[4],  v0, fmaf(qq[5],  v1, fmaf(qq[6],  v2, qq[7]  * v3)));
            float n2 = fmaf(qq[8],  v0, fmaf(qq[9],  v1, fmaf(qq[10], v2, qq[11] * v3)));
            float n3 = fmaf(qq[12], v0, fmaf(qq[13], v1, fmaf(qq[14], v2, qq[15] * v3)));
            v0 = n0; v1 = n1; v2 = n2; v3 = n3;
        }
        out[b2] = v0;
    }
}

// ---------------------------------------------------------------------------
// FALLBACK kernels (round-4 path, proven within 15 MB workspace)
// ---------------------------------------------------------------------------
__global__ void __launch_bounds__(TPBS)
seg_slow(const float* __restrict__ X, const float* __restrict__ Tc,
         float* __restrict__ P) {
    __shared__ float4 tcs4[SEGS * 12];
    __shared__ float2 xxs[TPBS][SEGS + 1];
    int t  = threadIdx.x;
    int s  = blockIdx.y;
    int ls = s * SEGS;
    int b0 = blockIdx.x * TPBS;

    const float4* tg = (const float4*)Tc + (size_t)ls * 12;
    #pragma unroll
    for (int i = t; i < SEGS * 12; i += TPBS) tcs4[i] = tg[i];

    const float2* Xp = (const float2*)X;
    for (int idx = t; idx < SEGS * TPBS; idx += TPBS) {
        int col  = idx % SEGS;
        int row  = idx / SEGS;
        int site = ls + 1 + col;
        site = site < (N_SITES - 1) ? site : (N_SITES - 1);
        float2 xv = Xp[(size_t)(b0 + row) * N_SITES + site];
        float inv = __builtin_amdgcn_rcpf(fmaf(xv.x, xv.x, xv.y * xv.y));
        xxs[row][col] = make_float2(xv.x * xv.x * inv, xv.x * xv.y * inv);
    }
    __syncthreads();

    float pA[16], pB[16];
    #pragma unroll
    for (int i = 0; i < 16; ++i) pA[i] = (i % 5 == 0) ? 1.f : 0.f;

#define STEP(SRC, DST, I)                                                       \
    {                                                                           \
        float2 xx = xxs[t][I];                                                  \
        float R[16];                                                            \
        _Pragma("unroll")                                                       \
        for (int r = 0; r < 4; ++r) {                                           \
            float4 cv = tcs4[(I) * 12 + r];                                     \
            float4 dv = tcs4[(I) * 12 + 4 + r];                                 \
            float4 bv = tcs4[(I) * 12 + 8 + r];                                 \
            R[r * 4 + 0] = fmaf(bv.x, xx.y, fmaf(dv.x, xx.x, cv.x));            \
            R[r * 4 + 1] = fmaf(bv.y, xx.y, fmaf(dv.y, xx.x, cv.y));            \
            R[r * 4 + 2] = fmaf(bv.z, xx.y, fmaf(dv.z, xx.x, cv.z));            \
            R[r * 4 + 3] = fmaf(bv.w, xx.y, fmaf(dv.w, xx.x, cv.w));            \
        }                                                                       \
        _Pragma("unroll")                                                       \
        for (int r = 0; r < 4; ++r) {                                           \
            _Pragma("unroll")                                                   \
            for (int cc = 0; cc < 4; ++cc)                                      \
                DST[r * 4 + cc] =                                               \
                    fmaf(R[r * 4 + 0], SRC[cc],                                 \
                    fmaf(R[r * 4 + 1], SRC[4 + cc],                             \
                    fmaf(R[r * 4 + 2], SRC[8 + cc],                             \
                         R[r * 4 + 3] * SRC[12 + cc])));                        \
        }                                                                       \
    }

    #pragma unroll
    for (int i = 0; i < SEGS; i += 2) {
        STEP(pA, pB, i);
        STEP(pB, pA, i + 1);
    }
#undef STEP

    int b = b0 + t;
    #pragma unroll
    for (int i = 0; i < 16; ++i)
        P[((size_t)(s * 16 + i)) * B_BATCH + b] = pA[i];
}

__global__ void __launch_bounds__(256)
combine28(const float* __restrict__ X, const float* __restrict__ P,
          float* __restrict__ out) {
    __shared__ float q[256][17];
    int t  = threadIdx.x;
    int j  = t >> 6;
    int bl = t & 63;
    int b  = blockIdx.x * 64 + bl;

    float qa[16], qb[16];
    #pragma unroll
    for (int i = 0; i < 16; ++i) qa[i] = (i % 5 == 0) ? 1.f : 0.f;

#define CSTEP(SRC, DST, K)                                                      \
    {                                                                           \
        float m[16];                                                            \
        _Pragma("unroll")                                                       \
        for (int i = 0; i < 16; ++i)                                            \
            m[i] = P[((size_t)((j * 7 + (K)) * 16 + i)) * B_BATCH + b];         \
        _Pragma("unroll")                                                       \
        for (int r = 0; r < 4; ++r) {                                           \
            _Pragma("unroll")                                                   \
            for (int cc = 0; cc < 4; ++cc)                                      \
                DST[r * 4 + cc] =                                               \
                    fmaf(m[r * 4 + 0], SRC[cc],                                 \
                    fmaf(m[r * 4 + 1], SRC[4 + cc],                             \
                    fmaf(m[r * 4 + 2], SRC[8 + cc],                             \
                         m[r * 4 + 3] * SRC[12 + cc])));                        \
        }                                                                       \
    }
    CSTEP(qa, qb, 0); CSTEP(qb, qa, 1);
    CSTEP(qa, qb, 2); CSTEP(qb, qa, 3);
    CSTEP(qa, qb, 4); CSTEP(qb, qa, 5);
    CSTEP(qa, qb, 6);
#undef CSTEP

    #pragma unroll
    for (int i = 0; i < 16; ++i) q[t][i] = qb[i];
    __syncthreads();

    if (t < 64) {
        int b2 = blockIdx.x * 64 + t;
        const float2* Xp = (const float2*)X;
        float2 xv = Xp[(size_t)b2 * N_SITES];
        float inv = __builtin_amdgcn_rcpf(fmaf(xv.x, xv.x, xv.y * xv.y));
        float v0 = xv.x * xv.x * inv;
        float v1 = xv.y * xv.y * inv;
        float v2 = xv.x * xv.y * inv;
        float v3 = 0.f;
        #pragma unroll
        for (int jj = 0; jj < 4; ++jj) {
            const float* qq = q[jj * 64 + t];
            float n0 = fmaf(qq[0],  v0, fmaf(qq[1],  v1, fmaf(qq[2],  v2, qq[3]  * v3)));
            float n1 = fmaf(qq[4],  v0, fmaf(qq[5],  v1, fmaf(qq[6],  v2, qq[7]  * v3)));
            float n2 = fmaf(qq[8],  v0, fmaf(qq[9],  v1, fmaf(qq[10], v2, qq[11] * v3)));
            float n3 = fmaf(qq[12], v0, fmaf(qq[13], v1, fmaf(qq[14], v2, qq[15] * v3)));
            v0 = n0; v1 = n1; v2 = n2; v3 = n3;
        }
        out[b2] = v0;
    }
}

// ---------------------------------------------------------------------------
extern "C" void kernel_launch(void* const* d_in, const int* in_sizes, int n_in,
                              void* d_out, int out_size, void* d_ws, size_t ws_size,
                              hipStream_t stream) {
    const float* X  = (const float*)d_in[0];
    const float* kr = (const float*)d_in[1];
    const float* ki = (const float*)d_in[2];
    float* out = (float*)d_out;

    float* Tc = (float*)d_ws;
    const size_t Tb  = (size_t)L_PAD * 48 * sizeof(float);         // 150,528 (256-mult)
    const size_t Pfb = (size_t)GF * 16 * B_BATCH * sizeof(float);  // 29,360,128

    build_T<<<L_PAD, 256, 0, stream>>>(kr, ki, Tc);

    if (ws_size >= Tb + Pfb) {
        // FAST path: per-thread own-row loads, no transpose staging
        float* P = (float*)((char*)d_ws + Tb);
        dim3 gs(B_BATCH / 256, GF);
        seg_fused<<<gs, 256, 0, stream>>>(X, Tc, P);
        combine56<<<B_BATCH / 32, 256, 0, stream>>>(X, P, out);
    } else {
        // FALLBACK (round-4 path, 14.8 MB)
        float* P = (float*)((char*)d_ws + Tb);
        dim3 gs(B_BATCH / TPBS, GS);
        seg_slow<<<gs, TPBS, 0, stream>>>(X, Tc, P);
        combine28<<<B_BATCH / 64, 256, 0, stream>>>(X, P, out);
    }
}

// Round 11
// 37.932 us; speedup vs baseline: 1.2701x; 1.1472x over previous
//
#include <hip/hip_runtime.h>

#define L_LAYERS 783
#define L_PAD    784           // = SEGF*GF
#define B_BATCH  8192
#define N_SITES  784
#define K_KRAUS  16

#define SEGF     14
#define GF       56
#define TCW      36            // floats per layer (rows 0,2,3 of C,D,B)
#define PW       12            // floats per P matrix (rows 0,2,3)

// ---------------------------------------------------------------------------
// Hermitian-reduced + trace-preserving formulation.
// State v = (s00, s11, u, w).  Per layer v' = R v with
//   R = C + D*xx0 + B*xx1  (48 coeffs), but CPTP gives R[0]+R[1] = [1,1,0,0],
// so only rows {0,2,3} are stored (36 floats: C(12) | D(12) | B(12)) and
// row 1 of any product is reconstructed as  P[1][c] = [1,1,0,0][c] - P[0][c].
// Pad layers (l >= 783): R = I.
// ---------------------------------------------------------------------------
__global__ void __launch_bounds__(256)
build_T(const float* __restrict__ kr, const float* __restrict__ ki,
        float* __restrict__ Tc) {
    __shared__ float lr[K_KRAUS * 16];
    __shared__ float li[K_KRAUS * 16];
    __shared__ float gr[32], gi[32];
    int l = blockIdx.x;
    int t = threadIdx.x;
    float* o = Tc + (size_t)l * TCW;

    if (l >= L_LAYERS) {                        // identity pad layer
        if (t < 12) {
            int r3 = t >> 2, col = t & 3;
            int row = (r3 == 0) ? 0 : r3 + 1;   // 0,2,3
            o[t]      = (col == row) ? 1.f : 0.f;  // C = I (rows 0,2,3)
            o[12 + t] = 0.f;                       // D = 0
            o[24 + t] = 0.f;                       // B = 0
        }
        return;
    }

    lr[t] = kr[(size_t)l * 256 + t];
    li[t] = ki[(size_t)l * 256 + t];
    __syncthreads();

    // Gram entries for ci=0 ((c,d)=(0,0)) and ci=1 ((0,1)) only; row1 dropped.
    if (t < 128) {
        int e = t >> 2, chunk = t & 3;          // e in 0..31
        int ci = e >> 4;                        // 0,1
        int c = 0, d = ci;                      // (0,0),(0,1)
        int m = (e >> 2) & 3, q = e & 3;
        int i1 = m >> 1, j1 = m & 1, i2 = q >> 1, j2 = q & 1;
        int off1 = c * 4 + 2 * i1 + i2;
        int off2 = d * 4 + 2 * j1 + j2;
        float ar = 0.f, ai = 0.f;
        #pragma unroll
        for (int kk = 0; kk < 4; ++kk) {
            int kbase = (chunk * 4 + kk) * 16;
            #pragma unroll
            for (int a = 0; a < 2; ++a) {
                int x1 = kbase + a * 8 + off1;
                int x2 = kbase + a * 8 + off2;
                float k1r = lr[x1], k1i = li[x1];
                float k2r = lr[x2], k2i = li[x2];
                ar += k1r * k2r + k1i * k2i;    // K1 * conj(K2)
                ai += k1i * k2r - k1r * k2i;
            }
        }
        ar += __shfl_xor(ar, 1); ar += __shfl_xor(ar, 2);
        ai += __shfl_xor(ai, 1); ai += __shfl_xor(ai, 2);
        if (chunk == 0) { gr[e] = ar; gi[e] = ai; }
    }
    __syncthreads();

    if (t < 12) {
        int r3 = t >> 2, col = t & 3;
        int row = (r3 == 0) ? 0 : r3 + 1;       // 0,2,3
        int ci = (row == 0) ? 0 : 1;
        int base = ci * 16;
        float Ur[4], Ui[4];
        #pragma unroll
        for (int q = 0; q < 4; ++q) {
            if (col == 0)      { Ur[q] = gr[base + q];      Ui[q] = gi[base + q]; }
            else if (col == 1) { Ur[q] = gr[base + 12 + q]; Ui[q] = gi[base + 12 + q]; }
            else {
                float t1r = gr[base + 4 + q], t1i = gi[base + 4 + q];
                float t2r = gr[base + 8 + q], t2i = gi[base + 8 + q];
                if (col == 2) { Ur[q] = t1r + t2r;    Ui[q] = t1i + t2i; }
                else          { Ur[q] = -(t1i - t2i); Ui[q] = t1r - t2r; }   // i*(T1-T2)
            }
        }
        float A, Bc, Cc;
        if (row == 3) { A = Ui[0]; Bc = Ui[1] + Ui[2]; Cc = Ui[3]; }
        else          { A = Ur[0]; Bc = Ur[1] + Ur[2]; Cc = Ur[3]; }
        o[t]      = Cc;
        o[12 + t] = A - Cc;
        o[24 + t] = Bc;
    }
}

// ---------------------------------------------------------------------------
// Kernel 2: per (batch-chunk, segment) product of SEGF transfer matrices.
// Tc via SCALAR loads (wave-uniform address -> s_load, K$); X staged through
// LDS once (R7 mapping). pA/pB hold rows {0,2,3} only; implicit row1.
// P stored SoA: P[(s*12 + i) * B + b].
// ---------------------------------------------------------------------------
__global__ void __launch_bounds__(256, 4)
seg_fused(const float* __restrict__ X, const float* __restrict__ Tc,
          float* __restrict__ P) {
    __shared__ float2 xxs[256 * SEGF];          // 28672 B
    int t  = threadIdx.x;
    int s  = blockIdx.y;
    int ls = s * SEGF;
    int b0 = blockIdx.x * 256;
    const float* tl0 = Tc + (size_t)ls * TCW;   // wave-uniform -> s_load
    const float2* Xp = (const float2*)X;

    // coalesced transpose stage (proven R7 pattern)
    #pragma unroll
    for (int e = 0; e < SEGF; ++e) {
        int idx  = t + e * 256;                 // 0..3583
        int row  = idx / SEGF;
        int col  = idx - row * SEGF;
        int site = ls + 1 + col;
        site = site < (N_SITES - 1) ? site : (N_SITES - 1);   // pad clamp
        float2 xv = Xp[(size_t)(b0 + row) * N_SITES + site];
        float inv = __builtin_amdgcn_rcpf(fmaf(xv.x, xv.x, xv.y * xv.y));
        xxs[row * SEGF + col] = make_float2(xv.x * xv.x * inv, xv.x * xv.y * inv);
    }
    __syncthreads();

    float pA[12], pB[12];
    // identity rows {0,2,3}: [1,0,0,0],[0,0,1,0],[0,0,0,1]
    #pragma unroll
    for (int i = 0; i < 12; ++i) pA[i] = 0.f;
    pA[0] = 1.f; pA[6] = 1.f; pA[11] = 1.f;

#define STEP(SRC, DST, I)                                                       \
    {                                                                           \
        const float* tl = tl0 + (I) * TCW;      /* uniform -> s_load */         \
        float2 xx = xxs[t * SEGF + (I)];                                        \
        float R[12];                                                            \
        _Pragma("unroll")                                                       \
        for (int e = 0; e < 12; ++e)                                            \
            R[e] = fmaf(tl[24 + e], xx.y, fmaf(tl[12 + e], xx.x, tl[e]));       \
        _Pragma("unroll")                                                       \
        for (int r = 0; r < 3; ++r) {                                           \
            float Rd = R[r * 4 + 0] - R[r * 4 + 1];                             \
            float R1 = R[r * 4 + 1];                                            \
            _Pragma("unroll")                                                   \
            for (int cc = 0; cc < 4; ++cc) {                                    \
                float base = (cc < 2) ? R1 : 0.f;                               \
                DST[r * 4 + cc] =                                               \
                    fmaf(Rd, SRC[cc],                                           \
                    fmaf(R[r * 4 + 2], SRC[4 + cc],                             \
                    fmaf(R[r * 4 + 3], SRC[8 + cc], base)));                    \
            }                                                                   \
        }                                                                       \
    }

    #pragma unroll
    for (int i = 0; i < SEGF; i += 2) {         // SEGF even -> ends in pA
        STEP(pA, pB, i);
        STEP(pB, pA, i + 1);
    }
#undef STEP

    int b = b0 + t;
    #pragma unroll
    for (int i = 0; i < 12; ++i)
        P[((size_t)(s * PW + i)) * B_BATCH + b] = pA[i];
}

// ---------------------------------------------------------------------------
// Kernel 3: two-level combine (8 groups x 7-chain, then 8-chain).
// Row 1 of each P reconstructed via trace conservation: n1 = v0 + v1 - n0.
// ---------------------------------------------------------------------------
__global__ void __launch_bounds__(256)
combine56(const float* __restrict__ X, const float* __restrict__ P,
          float* __restrict__ out) {
    __shared__ float q[256][13];
    int t = threadIdx.x;
    int j = t >> 5, bl = t & 31;
    int b = blockIdx.x * 32 + bl;

    // chain through 7 segment matrices applied to... we carry the matrix
    // product rows {0,2,3} like seg does, starting from identity.
    float qa[12], qb[12];
    #pragma unroll
    for (int i = 0; i < 12; ++i) qa[i] = 0.f;
    qa[0] = 1.f; qa[6] = 1.f; qa[11] = 1.f;

#define CSTEP(SRC, DST, K)                                                      \
    {                                                                           \
        float m[12];                                                            \
        _Pragma("unroll")                                                       \
        for (int i = 0; i < 12; ++i)                                            \
            m[i] = P[((size_t)((j * 7 + (K)) * PW + i)) * B_BATCH + b];         \
        _Pragma("unroll")                                                       \
        for (int r = 0; r < 3; ++r) {                                           \
            float Rd = m[r * 4 + 0] - m[r * 4 + 1];                             \
            float R1 = m[r * 4 + 1];                                            \
            _Pragma("unroll")                                                   \
            for (int cc = 0; cc < 4; ++cc) {                                    \
                float base = (cc < 2) ? R1 : 0.f;                               \
                DST[r * 4 + cc] =                                               \
                    fmaf(Rd, SRC[cc],                                           \
                    fmaf(m[r * 4 + 2], SRC[4 + cc],                             \
                    fmaf(m[r * 4 + 3], SRC[8 + cc], base)));                    \
            }                                                                   \
        }                                                                       \
    }
    CSTEP(qa, qb, 0); CSTEP(qb, qa, 1);
    CSTEP(qa, qb, 2); CSTEP(qb, qa, 3);
    CSTEP(qa, qb, 4); CSTEP(qb, qa, 5);
    CSTEP(qa, qb, 6);                          // result in qb
#undef CSTEP

    #pragma unroll
    for (int i = 0; i < 12; ++i) q[t][i] = qb[i];
    __syncthreads();

    if (t < 32) {
        int b2 = blockIdx.x * 32 + t;
        const float2* Xp = (const float2*)X;
        float2 xv = Xp[(size_t)b2 * N_SITES];
        float inv = __builtin_amdgcn_rcpf(fmaf(xv.x, xv.x, xv.y * xv.y));
        float v0 = xv.x * xv.x * inv;          // s00
        float v1 = xv.y * xv.y * inv;          // s11
        float v2 = xv.x * xv.y * inv;          // u
        float v3 = 0.f;                        // w
        #pragma unroll
        for (int jj = 0; jj < 8; ++jj) {
            const float* qq = q[jj * 32 + t];
            float n0 = fmaf(qq[0], v0, fmaf(qq[1], v1, fmaf(qq[2],  v2, qq[3]  * v3)));
            float n2 = fmaf(qq[4], v0, fmaf(qq[5], v1, fmaf(qq[6],  v2, qq[7]  * v3)));
            float n3 = fmaf(qq[8], v0, fmaf(qq[9], v1, fmaf(qq[10], v2, qq[11] * v3)));
            float n1 = (v0 + v1) - n0;         // trace conservation
            v0 = n0; v1 = n1; v2 = n2; v3 = n3;
        }
        out[b2] = v0;
    }
}

// ---------------------------------------------------------------------------
extern "C" void kernel_launch(void* const* d_in, const int* in_sizes, int n_in,
                              void* d_out, int out_size, void* d_ws, size_t ws_size,
                              hipStream_t stream) {
    const float* X  = (const float*)d_in[0];
    const float* kr = (const float*)d_in[1];
    const float* ki = (const float*)d_in[2];
    float* out = (float*)d_out;

    float* Tc = (float*)d_ws;
    const size_t Tb = ((size_t)L_PAD * TCW * sizeof(float) + 255) & ~(size_t)255; // ~113 KB
    float* P = (float*)((char*)d_ws + Tb);      // 56*12*8192*4 = 22.0 MB

    build_T<<<L_PAD, 256, 0, stream>>>(kr, ki, Tc);

    dim3 gs(B_BATCH / 256, GF);
    seg_fused<<<gs, 256, 0, stream>>>(X, Tc, P);

    combine56<<<B_BATCH / 32, 256, 0, stream>>>(X, P, out);
}

// Round 12
// 35.737 us; speedup vs baseline: 1.3481x; 1.0614x over previous
//
#include <hip/hip_runtime.h>

#define L_LAYERS 783
#define L_PAD    784           // = SEGF*GF
#define B_BATCH  8192
#define N_SITES  784
#define K_KRAUS  16

#define SEGF     14
#define GF       56
#define TCW      36            // floats per layer (rows 0,2,3 of C,D,B)
#define PW       12            // floats per P matrix (rows 0,2,3)

// ---------------------------------------------------------------------------
// Hermitian-reduced + trace-preserving formulation.
// State v = (s00, s11, u, w).  Per layer v' = R v with
//   R = C + D*xx0 + B*xx1, and CPTP gives R[0]+R[1] = [1,1,0,0]:
// only rows {0,2,3} stored (36 floats: C(12) | D(12) | B(12)); row 1 of any
// product is reconstructed as P[1][c] = [1,1,0,0][c] - P[0][c].
// Pad layers (l >= 783): R = I.
// ---------------------------------------------------------------------------
__global__ void __launch_bounds__(256)
build_T(const float* __restrict__ kr, const float* __restrict__ ki,
        float* __restrict__ Tc) {
    __shared__ float lr[K_KRAUS * 16];
    __shared__ float li[K_KRAUS * 16];
    __shared__ float gr[32], gi[32];
    int l = blockIdx.x;
    int t = threadIdx.x;
    float* o = Tc + (size_t)l * TCW;

    if (l >= L_LAYERS) {                        // identity pad layer
        if (t < 12) {
            int r3 = t >> 2, col = t & 3;
            int row = (r3 == 0) ? 0 : r3 + 1;   // 0,2,3
            o[t]      = (col == row) ? 1.f : 0.f;
            o[12 + t] = 0.f;
            o[24 + t] = 0.f;
        }
        return;
    }

    lr[t] = kr[(size_t)l * 256 + t];
    li[t] = ki[(size_t)l * 256 + t];
    __syncthreads();

    if (t < 128) {
        int e = t >> 2, chunk = t & 3;          // e in 0..31
        int ci = e >> 4;                        // 0,1
        int c = 0, d = ci;                      // (0,0),(0,1)
        int m = (e >> 2) & 3, q = e & 3;
        int i1 = m >> 1, j1 = m & 1, i2 = q >> 1, j2 = q & 1;
        int off1 = c * 4 + 2 * i1 + i2;
        int off2 = d * 4 + 2 * j1 + j2;
        float ar = 0.f, ai = 0.f;
        #pragma unroll
        for (int kk = 0; kk < 4; ++kk) {
            int kbase = (chunk * 4 + kk) * 16;
            #pragma unroll
            for (int a = 0; a < 2; ++a) {
                int x1 = kbase + a * 8 + off1;
                int x2 = kbase + a * 8 + off2;
                float k1r = lr[x1], k1i = li[x1];
                float k2r = lr[x2], k2i = li[x2];
                ar += k1r * k2r + k1i * k2i;    // K1 * conj(K2)
                ai += k1i * k2r - k1r * k2i;
            }
        }
        ar += __shfl_xor(ar, 1); ar += __shfl_xor(ar, 2);
        ai += __shfl_xor(ai, 1); ai += __shfl_xor(ai, 2);
        if (chunk == 0) { gr[e] = ar; gi[e] = ai; }
    }
    __syncthreads();

    if (t < 12) {
        int r3 = t >> 2, col = t & 3;
        int row = (r3 == 0) ? 0 : r3 + 1;       // 0,2,3
        int ci = (row == 0) ? 0 : 1;
        int base = ci * 16;
        float Ur[4], Ui[4];
        #pragma unroll
        for (int q = 0; q < 4; ++q) {
            if (col == 0)      { Ur[q] = gr[base + q];      Ui[q] = gi[base + q]; }
            else if (col == 1) { Ur[q] = gr[base + 12 + q]; Ui[q] = gi[base + 12 + q]; }
            else {
                float t1r = gr[base + 4 + q], t1i = gi[base + 4 + q];
                float t2r = gr[base + 8 + q], t2i = gi[base + 8 + q];
                if (col == 2) { Ur[q] = t1r + t2r;    Ui[q] = t1i + t2i; }
                else          { Ur[q] = -(t1i - t2i); Ui[q] = t1r - t2r; }   // i*(T1-T2)
            }
        }
        float A, Bc, Cc;
        if (row == 3) { A = Ui[0]; Bc = Ui[1] + Ui[2]; Cc = Ui[3]; }
        else          { A = Ur[0]; Bc = Ur[1] + Ur[2]; Cc = Ur[3]; }
        o[t]      = Cc;
        o[12 + t] = A - Cc;
        o[24 + t] = Bc;
    }
}

// ---------------------------------------------------------------------------
// Kernel 2: per (batch-chunk, segment) product of SEGF transfer matrices.
// All wide ops: staging 7x dwordx4 loads + 7x b128 LDS writes; consume 7x
// b128 LDS reads (1 per layer-pair); P out as 3x dwordx4. Tc via scalar
// s_load (wave-uniform). pA/pB hold rows {0,2,3}; implicit row1.
// ---------------------------------------------------------------------------
__global__ void __launch_bounds__(256, 4)
seg_fused(const float* __restrict__ X, const float* __restrict__ Tc,
          float* __restrict__ P) {
    __shared__ float4 xxs4[256 * 7];            // 28672 B; [row*7 + pair]
    int t  = threadIdx.x;
    int s  = blockIdx.y;
    int ls = s * SEGF;
    int b0 = blockIdx.x * 256;
    const float* tl0 = Tc + (size_t)ls * TCW;   // wave-uniform -> s_load
    const float2* Xp = (const float2*)X;

    // stage: pair p covers sites (ls+1+2p, ls+2+2p); pair start is odd so
    // only the final pair of the last segment can touch site 784 -> clamp
    // start to 782 and take .zw for the real site (pad layer xx is don't-care).
    #pragma unroll
    for (int e = 0; e < 7; ++e) {
        int idx  = t + e * 256;                 // 0..1791
        int row  = idx / 7;
        int p    = idx - row * 7;
        int s0   = ls + 1 + 2 * p;
        bool cl  = (s0 > N_SITES - 2);          // only s=55, p=6
        int  s0c = cl ? (N_SITES - 2) : s0;
        float4 f = *(const float4*)(Xp + (size_t)(b0 + row) * N_SITES + s0c);
        float ax = cl ? f.z : f.x;
        float ay = cl ? f.w : f.y;
        float inva = __builtin_amdgcn_rcpf(fmaf(ax, ax, ay * ay));
        float invb = __builtin_amdgcn_rcpf(fmaf(f.z, f.z, f.w * f.w));
        xxs4[row * 7 + p] = make_float4(ax * ax * inva, ax * ay * inva,
                                        f.z * f.z * invb, f.z * f.w * invb);
    }
    __syncthreads();

    float pA[12], pB[12];
    #pragma unroll
    for (int i = 0; i < 12; ++i) pA[i] = 0.f;
    pA[0] = 1.f; pA[6] = 1.f; pA[11] = 1.f;     // identity rows {0,2,3}

#define STEPX(SRC, DST, I, XX0, XX1)                                            \
    {                                                                           \
        const float* tl = tl0 + (I) * TCW;      /* uniform -> s_load */         \
        float R[12];                                                            \
        _Pragma("unroll")                                                       \
        for (int e = 0; e < 12; ++e)                                            \
            R[e] = fmaf(tl[24 + e], (XX1), fmaf(tl[12 + e], (XX0), tl[e]));     \
        _Pragma("unroll")                                                       \
        for (int r = 0; r < 3; ++r) {                                           \
            float Rd = R[r * 4 + 0] - R[r * 4 + 1];                             \
            float R1 = R[r * 4 + 1];                                            \
            _Pragma("unroll")                                                   \
            for (int cc = 0; cc < 4; ++cc) {                                    \
                float base = (cc < 2) ? R1 : 0.f;                               \
                DST[r * 4 + cc] =                                               \
                    fmaf(Rd, SRC[cc],                                           \
                    fmaf(R[r * 4 + 2], SRC[4 + cc],                             \
                    fmaf(R[r * 4 + 3], SRC[8 + cc], base)));                    \
            }                                                                   \
        }                                                                       \
    }

    #pragma unroll
    for (int p = 0; p < 7; ++p) {               // 2 layers per LDS read
        float4 xp4 = xxs4[t * 7 + p];
        STEPX(pA, pB, 2 * p,     xp4.x, xp4.y);
        STEPX(pB, pA, 2 * p + 1, xp4.z, xp4.w);
    }
#undef STEPX

    int b = b0 + t;
    float4* P4 = (float4*)P;
    #pragma unroll
    for (int k = 0; k < 3; ++k)
        P4[((size_t)(s * 3 + k)) * B_BATCH + b] =
            make_float4(pA[4 * k], pA[4 * k + 1], pA[4 * k + 2], pA[4 * k + 3]);
}

// ---------------------------------------------------------------------------
// Kernel 3: two-level combine (8 groups x 7-chain, then 8-chain).
// Row 1 reconstructed via trace conservation.
// ---------------------------------------------------------------------------
__global__ void __launch_bounds__(256)
combine56(const float* __restrict__ X, const float* __restrict__ P,
          float* __restrict__ out) {
    __shared__ float q[256][13];
    int t = threadIdx.x;
    int j = t >> 5, bl = t & 31;
    int b = blockIdx.x * 32 + bl;
    const float4* P4 = (const float4*)P;

    float qa[12], qb[12];
    #pragma unroll
    for (int i = 0; i < 12; ++i) qa[i] = 0.f;
    qa[0] = 1.f; qa[6] = 1.f; qa[11] = 1.f;

#define CSTEP(SRC, DST, K)                                                      \
    {                                                                           \
        float m[12];                                                            \
        _Pragma("unroll")                                                       \
        for (int k = 0; k < 3; ++k) {                                           \
            float4 mv = P4[((size_t)((j * 7 + (K)) * 3 + k)) * B_BATCH + b];    \
            m[4 * k + 0] = mv.x; m[4 * k + 1] = mv.y;                           \
            m[4 * k + 2] = mv.z; m[4 * k + 3] = mv.w;                           \
        }                                                                       \
        _Pragma("unroll")                                                       \
        for (int r = 0; r < 3; ++r) {                                           \
            float Rd = m[r * 4 + 0] - m[r * 4 + 1];                             \
            float R1 = m[r * 4 + 1];                                            \
            _Pragma("unroll")                                                   \
            for (int cc = 0; cc < 4; ++cc) {                                    \
                float base = (cc < 2) ? R1 : 0.f;                               \
                DST[r * 4 + cc] =                                               \
                    fmaf(Rd, SRC[cc],                                           \
                    fmaf(m[r * 4 + 2], SRC[4 + cc],                             \
                    fmaf(m[r * 4 + 3], SRC[8 + cc], base)));                    \
            }                                                                   \
        }                                                                       \
    }
    CSTEP(qa, qb, 0); CSTEP(qb, qa, 1);
    CSTEP(qa, qb, 2); CSTEP(qb, qa, 3);
    CSTEP(qa, qb, 4); CSTEP(qb, qa, 5);
    CSTEP(qa, qb, 6);                          // result in qb
#undef CSTEP

    #pragma unroll
    for (int i = 0; i < 12; ++i) q[t][i] = qb[i];
    __syncthreads();

    if (t < 32) {
        int b2 = blockIdx.x * 32 + t;
        const float2* Xp = (const float2*)X;
        float2 xv = Xp[(size_t)b2 * N_SITES];
        float inv = __builtin_amdgcn_rcpf(fmaf(xv.x, xv.x, xv.y * xv.y));
        float v0 = xv.x * xv.x * inv;          // s00
        float v1 = xv.y * xv.y * inv;          // s11
        float v2 = xv.x * xv.y * inv;          // u
        float v3 = 0.f;                        // w
        #pragma unroll
        for (int jj = 0; jj < 8; ++jj) {
            const float* qq = q[jj * 32 + t];
            float n0 = fmaf(qq[0], v0, fmaf(qq[1], v1, fmaf(qq[2],  v2, qq[3]  * v3)));
            float n2 = fmaf(qq[4], v0, fmaf(qq[5], v1, fmaf(qq[6],  v2, qq[7]  * v3)));
            float n3 = fmaf(qq[8], v0, fmaf(qq[9], v1, fmaf(qq[10], v2, qq[11] * v3)));
            float n1 = (v0 + v1) - n0;         // trace conservation
            v0 = n0; v1 = n1; v2 = n2; v3 = n3;
        }
        out[b2] = v0;
    }
}

// ---------------------------------------------------------------------------
extern "C" void kernel_launch(void* const* d_in, const int* in_sizes, int n_in,
                              void* d_out, int out_size, void* d_ws, size_t ws_size,
                              hipStream_t stream) {
    const float* X  = (const float*)d_in[0];
    const float* kr = (const float*)d_in[1];
    const float* ki = (const float*)d_in[2];
    float* out = (float*)d_out;

    float* Tc = (float*)d_ws;
    const size_t Tb = ((size_t)L_PAD * TCW * sizeof(float) + 255) & ~(size_t)255;
    float* P = (float*)((char*)d_ws + Tb);      // 56*12*8192*4 = 22.0 MB

    build_T<<<L_PAD, 256, 0, stream>>>(kr, ki, Tc);

    dim3 gs(B_BATCH / 256, GF);
    seg_fused<<<gs, 256, 0, stream>>>(X, Tc, P);

    combine56<<<B_BATCH / 32, 256, 0, stream>>>(X, P, out);
}